// Round 1
// baseline (797.660 us; speedup 1.0000x reference)
//
#include <hip/hip_runtime.h>

#define PI_F 3.14159265358979323846f
#define LDX 132  // padded LDS row stride (floats); 132%32=4 breaks bank aliasing, keeps 16B align

__device__ __forceinline__ void ntk_next(float S, float& s_new, float& ds) {
    S = fminf(fmaxf(S, -0.9999f), 0.9999f);
    const float th = acosf(S);
    const float pmt = PI_F - th;
    ds = pmt / PI_F;
    s_new = (S * pmt + sqrtf(1.0f - S * S)) / PI_F;
}

// ---------------- per-graph precompute: w_S, d0_S, d0_T, z_T ----------------
__global__ __launch_bounds__(256) void precompute_kernel(
    const float* __restrict__ U_S, const float* __restrict__ V_S,
    const float* __restrict__ X_S, const float* __restrict__ X_T,
    const float* __restrict__ A_T,
    float* __restrict__ wS, float* __restrict__ d0S,
    float* __restrict__ d0T, float* __restrict__ zT)
{
    const int g = blockIdx.x, tid = threadIdx.x;
    __shared__ float U[768], V[768], VU[256], VUp[256], t16[16], t2[16], r48[48];

    for (int i = tid; i < 768; i += 256) { U[i] = U_S[g*768 + i]; V[i] = V_S[g*768 + i]; }
    __syncthreads();
    {   // VU = V(16x48) @ U(48x16)
        const int i = tid >> 4, j = tid & 15;
        float s = 0.f;
        #pragma unroll 4
        for (int k = 0; k < 48; ++k) s += V[i*48 + k] * U[k*16 + j];
        VU[tid] = s;
    }
    if (tid < 16) { float s = 0.f; for (int a = 0; a < 48; ++a) s += U[a*16 + tid]; t16[tid] = s; }
    __syncthreads();
    {   // VUp = VU @ VU
        const int i = tid >> 4, j = tid & 15;
        float s = 0.f;
        #pragma unroll
        for (int k = 0; k < 16; ++k) s += VU[i*16 + k] * VU[k*16 + j];
        VUp[tid] = s;
    }
    __syncthreads();
    if (tid < 16) { float s = 0.f; for (int b = 0; b < 16; ++b) s += t16[b] * VUp[b*16 + tid]; t2[tid] = s; }
    __syncthreads();
    if (tid < 48) { float s = 0.f; for (int b = 0; b < 16; ++b) s += t2[b] * V[b*48 + tid]; wS[g*48 + tid] = s; }

    if (tid < 48) {
        const float* x = X_S + g*6144 + tid*128;
        float s = 0.f;
        #pragma unroll 4
        for (int d = 0; d < 128; ++d) s += x[d]*x[d];
        d0S[g*48 + tid] = sqrtf(s + 1e-4f);
        const float* xt = X_T + g*6144 + tid*128;
        float s2 = 0.f;
        #pragma unroll 4
        for (int d = 0; d < 128; ++d) s2 += xt[d]*xt[d];
        d0T[g*48 + tid] = sqrtf(s2 + 1e-4f);
        const float* A = A_T + g*2304;
        float rc = 0.f;
        for (int d = 0; d < 48; ++d) rc += A[d*48 + tid];
        r48[tid] = rc + 1e-4f;   // r = A'^T 1, A' = A + 1e-4 I
    }
    __syncthreads();
    if (tid < 48) {
        const float* A = A_T + g*2304;
        float s = 0.f;
        for (int d = 0; d < 48; ++d) s += A[d*48 + tid] * r48[d];
        zT[g*48 + tid] = s + 1e-4f * r48[tid];   // z = A'^T r
    }
}

// ---------------- per-pair kernel: K[N,M] = wA^T ntk(sigma) wB ----------------
__global__ __launch_bounds__(256) void pair_kernel(
    const float* __restrict__ XA, const float* __restrict__ XB,
    const float* __restrict__ dAg, const float* __restrict__ dBg,
    const float* __restrict__ wAg, const float* __restrict__ wBg,
    float* __restrict__ Kout, const int sym)
{
    const int M = blockIdx.x, N = blockIdx.y;
    if (sym && M < N) return;  // K_SS is symmetric
    const int tid = threadIdx.x;

    __shared__ float Xa[48*LDX], Xb[48*LDX];
    __shared__ float dA0[48], dA1[48], dB0[48], dB1[48], wA[48], wB[48];
    __shared__ float red[4];

    const float4* srcA = reinterpret_cast<const float4*>(XA + N*6144);
    const float4* srcB = reinterpret_cast<const float4*>(XB + M*6144);
    for (int f = tid; f < 1536; f += 256) {
        const int row = f >> 5, c4 = (f & 31) << 2;
        *reinterpret_cast<float4*>(&Xa[row*LDX + c4]) = srcA[f];
        *reinterpret_cast<float4*>(&Xb[row*LDX + c4]) = srcB[f];
    }
    if (tid < 48) {
        // C1 = S_next(0.9999): the diagonal-recursion constant
        const float s0 = 0.9999f;
        const float th0 = acosf(s0);
        const float c1 = (s0*(PI_F - th0) + sqrtf(1.f - s0*s0)) / PI_F;
        const float da = dAg[N*48 + tid];
        const float db = dBg[M*48 + tid];
        dA0[tid] = da; dA1[tid] = sqrtf(c1*da*da);
        dB0[tid] = db; dB1[tid] = sqrtf(c1*db*db);
        wA[tid] = wAg[N*48 + tid];
        wB[tid] = wBg[M*48 + tid];
    }
    __syncthreads();

    // 48x48 sigma, 16x16 thread grid of 3x3 register tiles
    const int b0 = (tid >> 4) * 3, c0 = (tid & 15) * 3;
    float acc[3][3] = {{0.f,0.f,0.f},{0.f,0.f,0.f},{0.f,0.f,0.f}};
    #pragma unroll 4
    for (int k4 = 0; k4 < 32; ++k4) {
        const float4 a0 = *reinterpret_cast<const float4*>(&Xa[(b0+0)*LDX + k4*4]);
        const float4 a1 = *reinterpret_cast<const float4*>(&Xa[(b0+1)*LDX + k4*4]);
        const float4 a2 = *reinterpret_cast<const float4*>(&Xa[(b0+2)*LDX + k4*4]);
        const float4 v0 = *reinterpret_cast<const float4*>(&Xb[(c0+0)*LDX + k4*4]);
        const float4 v1 = *reinterpret_cast<const float4*>(&Xb[(c0+1)*LDX + k4*4]);
        const float4 v2 = *reinterpret_cast<const float4*>(&Xb[(c0+2)*LDX + k4*4]);
        acc[0][0] += a0.x*v0.x + a0.y*v0.y + a0.z*v0.z + a0.w*v0.w;
        acc[0][1] += a0.x*v1.x + a0.y*v1.y + a0.z*v1.z + a0.w*v1.w;
        acc[0][2] += a0.x*v2.x + a0.y*v2.y + a0.z*v2.z + a0.w*v2.w;
        acc[1][0] += a1.x*v0.x + a1.y*v0.y + a1.z*v0.z + a1.w*v0.w;
        acc[1][1] += a1.x*v1.x + a1.y*v1.y + a1.z*v1.z + a1.w*v1.w;
        acc[1][2] += a1.x*v2.x + a1.y*v2.y + a1.z*v2.z + a1.w*v2.w;
        acc[2][0] += a2.x*v0.x + a2.y*v0.y + a2.z*v0.z + a2.w*v0.w;
        acc[2][1] += a2.x*v1.x + a2.y*v1.y + a2.z*v1.z + a2.w*v1.w;
        acc[2][2] += a2.x*v2.x + a2.y*v2.y + a2.z*v2.z + a2.w*v2.w;
    }

    // NTK recursion (2 MLP layers) + weighted sum
    float val = 0.f;
    #pragma unroll
    for (int i = 0; i < 3; ++i) {
        #pragma unroll
        for (int j = 0; j < 3; ++j) {
            const int b = b0 + i, c = c0 + j;
            float sig = acc[i][j] + 1e-4f;
            float ntk = sig;
            float s, ds;
            const float tmp0 = dA0[b]*dB0[c] + 1e-6f;
            ntk_next(sig / tmp0, s, ds);
            ntk = ntk * ds + s;
            sig = s * tmp0;
            const float tmp1 = dA1[b]*dB1[c] + 1e-6f;
            ntk_next(sig / tmp1, s, ds);
            ntk = ntk * ds + s;
            val += wA[b] * ntk * wB[c];
        }
    }

    // block reduction
    const int lane = tid & 63, wv = tid >> 6;
    #pragma unroll
    for (int off = 32; off > 0; off >>= 1) val += __shfl_down(val, off, 64);
    if (lane == 0) red[wv] = val;
    __syncthreads();
    if (tid == 0) {
        const float r = red[0] + red[1] + red[2] + red[3];
        Kout[N*96 + M] = r;
        if (sym && M != N) Kout[M*96 + N] = r;
    }
}

// ---------------- single-block: regularize, LU w/ partial pivoting, solve, pred ----------------
__global__ __launch_bounds__(256) void solve_pred_kernel(
    const float* __restrict__ Kss, const float* __restrict__ yS,
    const float* __restrict__ Kst, float* __restrict__ pred)
{
    const int tid = threadIdx.x;
    const int LDA = 109;  // 109%32=13, gcd(13,32)=1 -> conflict-friendly column walks
    __shared__ float aug[96*109];
    __shared__ float xk[10];
    __shared__ float lam;
    __shared__ int pidx;

    for (int idx = tid; idx < 96*96; idx += 256) aug[(idx/96)*LDA + (idx%96)] = Kss[idx];
    for (int idx = tid; idx < 960; idx += 256) aug[(idx/10)*LDA + 96 + (idx%10)] = yS[idx];
    __syncthreads();
    if (tid == 0) {
        float tr = 0.f;
        for (int i = 0; i < 96; ++i) tr += aug[i*LDA + i];
        lam = 1e-6f * tr / 96.f;
    }
    __syncthreads();
    if (tid < 96) aug[tid*LDA + tid] += lam;
    __syncthreads();

    // forward elimination with partial pivoting
    for (int k = 0; k < 96; ++k) {
        if (tid == 0) {
            int p = k; float best = fabsf(aug[k*LDA + k]);
            for (int i = k+1; i < 96; ++i) {
                const float a = fabsf(aug[i*LDA + k]);
                if (a > best) { best = a; p = i; }
            }
            pidx = p;
        }
        __syncthreads();
        const int p = pidx;
        if (p != k) {
            for (int j = tid; j < 106; j += 256) {
                const float t = aug[k*LDA + j];
                aug[k*LDA + j] = aug[p*LDA + j];
                aug[p*LDA + j] = t;
            }
        }
        __syncthreads();
        const float pv = aug[k*LDA + k];
        if (tid > k && tid < 96) {
            const float f = aug[tid*LDA + k] / pv;
            for (int j = k; j < 106; ++j)
                aug[tid*LDA + j] -= f * aug[k*LDA + j];
        }
        __syncthreads();
    }

    // back substitution (10 RHS)
    for (int k = 95; k >= 0; --k) {
        if (tid < 10) {
            const float v = aug[k*LDA + 96 + tid] / aug[k*LDA + k];
            xk[tid] = v;
            aug[k*LDA + 96 + tid] = v;
        }
        __syncthreads();
        for (int idx = tid; idx < k*10; idx += 256) {
            const int i = idx/10, c = idx%10;
            aug[i*LDA + 96 + c] -= aug[i*LDA + k] * xk[c];
        }
        __syncthreads();
    }

    // pred = K_ST^T @ alpha  (alpha lives in aug[:,96:106])
    for (int idx = tid; idx < 960; idx += 256) {
        const int t = idx/10, c = idx%10;
        float s = 0.f;
        for (int n = 0; n < 96; ++n) s += Kst[n*96 + t] * aug[n*LDA + 96 + c];
        pred[idx] = s;
    }
}

extern "C" void kernel_launch(void* const* d_in, const int* in_sizes, int n_in,
                              void* d_out, int out_size, void* d_ws, size_t ws_size,
                              hipStream_t stream)
{
    (void)in_sizes; (void)n_in; (void)out_size; (void)ws_size;
    const float* U_S = (const float*)d_in[0];
    const float* V_S = (const float*)d_in[1];
    const float* X_S = (const float*)d_in[2];
    const float* y_S = (const float*)d_in[3];
    const float* A_T = (const float*)d_in[4];
    const float* X_T = (const float*)d_in[5];

    float* out  = (float*)d_out;
    float* pred = out;         // (96,10)
    float* Kss  = out + 960;   // (96,96)

    float* ws  = (float*)d_ws;
    float* wS  = ws;             // 96*48
    float* d0S = ws + 4608;      // 96*48
    float* d0T = ws + 9216;      // 96*48
    float* zT  = ws + 13824;     // 96*48
    float* Kst = ws + 18432;     // 96*96

    precompute_kernel<<<96, 256, 0, stream>>>(U_S, V_S, X_S, X_T, A_T, wS, d0S, d0T, zT);
    dim3 grid(96, 96);
    pair_kernel<<<grid, 256, 0, stream>>>(X_S, X_S, d0S, d0S, wS, wS, Kss, 1);
    pair_kernel<<<grid, 256, 0, stream>>>(X_S, X_T, d0S, d0T, wS, zT, Kst, 0);
    solve_pred_kernel<<<1, 256, 0, stream>>>(Kss, y_S, Kst, pred);
}

// Round 2
// 375.337 us; speedup vs baseline: 2.1252x; 2.1252x over previous
//
#include <hip/hip_runtime.h>

#define PI_F 3.14159265358979323846f

typedef _Float16 half8 __attribute__((ext_vector_type(8)));
typedef float f32x4 __attribute__((ext_vector_type(4)));

__device__ __forceinline__ unsigned short f2h_bits(float v) {
    union { _Float16 h; unsigned short u; } x; x.h = (_Float16)v; return x.u;
}
__device__ __forceinline__ float h2f(unsigned short u) {
    union { unsigned short u; _Float16 h; } x; x.u = u; return (float)x.h;
}

__device__ __forceinline__ void ntk_next(float S, float& s_new, float& ds) {
    S = fminf(fmaxf(S, -0.9999f), 0.9999f);
    const float th = acosf(S);
    const float pmt = PI_F - th;
    ds = pmt / PI_F;
    s_new = (S * pmt + sqrtf(1.0f - S * S)) / PI_F;
}

// ---------------- per-graph precompute: w_S, z_T, f16(X), d0 from f16(X) ----------------
__global__ __launch_bounds__(256) void precompute_kernel(
    const float* __restrict__ U_S, const float* __restrict__ V_S,
    const float* __restrict__ X_S, const float* __restrict__ X_T,
    const float* __restrict__ A_T,
    float* __restrict__ wS, float* __restrict__ d0S,
    float* __restrict__ d0T, float* __restrict__ zT,
    unsigned short* __restrict__ XSh, unsigned short* __restrict__ XTh)
{
    const int g = blockIdx.x, tid = threadIdx.x;
    __shared__ float U[768], V[768], VU[256], VUp[256], t16[16], t2[16], r48[48];
    __shared__ unsigned int Xb[3072];

    for (int i = tid; i < 768; i += 256) { U[i] = U_S[g*768 + i]; V[i] = V_S[g*768 + i]; }
    __syncthreads();
    {   // VU = V(16x48) @ U(48x16)
        const int i = tid >> 4, j = tid & 15;
        float s = 0.f;
        #pragma unroll 4
        for (int k = 0; k < 48; ++k) s += V[i*48 + k] * U[k*16 + j];
        VU[tid] = s;
    }
    if (tid < 16) { float s = 0.f; for (int a = 0; a < 48; ++a) s += U[a*16 + tid]; t16[tid] = s; }
    __syncthreads();
    {   // VUp = VU @ VU
        const int i = tid >> 4, j = tid & 15;
        float s = 0.f;
        #pragma unroll
        for (int k = 0; k < 16; ++k) s += VU[i*16 + k] * VU[k*16 + j];
        VUp[tid] = s;
    }
    __syncthreads();
    if (tid < 16) { float s = 0.f; for (int b = 0; b < 16; ++b) s += t16[b] * VUp[b*16 + tid]; t2[tid] = s; }
    __syncthreads();
    if (tid < 48) { float s = 0.f; for (int b = 0; b < 16; ++b) s += t2[b] * V[b*48 + tid]; wS[g*48 + tid] = s; }

    // ---- X_S -> f16, d0S from rounded values ----
    for (int j = tid; j < 3072; j += 256) {
        const float2 xv = reinterpret_cast<const float2*>(X_S + g*6144)[j];
        const unsigned int u = (unsigned int)f2h_bits(xv.x) | ((unsigned int)f2h_bits(xv.y) << 16);
        Xb[j] = u;
        reinterpret_cast<unsigned int*>(XSh)[g*3072 + j] = u;
    }
    __syncthreads();
    if (tid < 48) {
        float s = 0.f;
        #pragma unroll 4
        for (int j = 0; j < 64; ++j) {
            const unsigned int u = Xb[tid*64 + j];
            const float lo = h2f((unsigned short)(u & 0xffffu));
            const float hi = h2f((unsigned short)(u >> 16));
            s += lo*lo + hi*hi;
        }
        d0S[g*48 + tid] = sqrtf(s + 1e-4f);
    }
    __syncthreads();
    // ---- X_T -> f16, d0T ----
    for (int j = tid; j < 3072; j += 256) {
        const float2 xv = reinterpret_cast<const float2*>(X_T + g*6144)[j];
        const unsigned int u = (unsigned int)f2h_bits(xv.x) | ((unsigned int)f2h_bits(xv.y) << 16);
        Xb[j] = u;
        reinterpret_cast<unsigned int*>(XTh)[g*3072 + j] = u;
    }
    __syncthreads();
    if (tid < 48) {
        float s = 0.f;
        #pragma unroll 4
        for (int j = 0; j < 64; ++j) {
            const unsigned int u = Xb[tid*64 + j];
            const float lo = h2f((unsigned short)(u & 0xffffu));
            const float hi = h2f((unsigned short)(u >> 16));
            s += lo*lo + hi*hi;
        }
        d0T[g*48 + tid] = sqrtf(s + 1e-4f);
    }

    // ---- z_T = A'^T (A'^T 1), A' = A + 1e-4 I ----
    if (tid < 48) {
        const float* A = A_T + g*2304;
        float rc = 0.f;
        for (int d = 0; d < 48; ++d) rc += A[d*48 + tid];
        r48[tid] = rc + 1e-4f;
    }
    __syncthreads();
    if (tid < 48) {
        const float* A = A_T + g*2304;
        float s = 0.f;
        for (int d = 0; d < 48; ++d) s += A[d*48 + tid] * r48[d];
        zT[g*48 + tid] = s + 1e-4f * r48[tid];
    }
}

// ---------------- pair kernel: one wave per (N,M) pair, MFMA f16 sigma ----------------
// pairs 0..4655: K_SS upper triangle (mirrored); 4656..13871: K_ST all pairs.
__global__ __launch_bounds__(256) void pair_kernel(
    const unsigned short* __restrict__ XSh, const unsigned short* __restrict__ XTh,
    const float* __restrict__ d0S, const float* __restrict__ d0T,
    const float* __restrict__ wS, const float* __restrict__ zT,
    float* __restrict__ Kss, float* __restrict__ Kst)
{
    const int wv = threadIdx.x >> 6, lane = threadIdx.x & 63;
    const int t = blockIdx.x * 4 + wv;
    if (t >= 13872) return;

    int Nn, Mm, isSS;
    const unsigned short *XA, *XB;
    const float *dA, *dB, *wA, *wB;
    if (t < 4656) {
        isSS = 1;
        int Ni = (int)((sqrtf(8.0f*(float)t + 1.0f) - 1.0f) * 0.5f);
        while (Ni*(Ni+1)/2 > t) --Ni;
        while ((Ni+1)*(Ni+2)/2 <= t) ++Ni;
        Nn = Ni; Mm = t - Ni*(Ni+1)/2;
        XA = XSh + Nn*6144; XB = XSh + Mm*6144;
        dA = d0S + Nn*48;   dB = d0S + Mm*48;
        wA = wS  + Nn*48;   wB = wS  + Mm*48;
    } else {
        isSS = 0;
        const int t2 = t - 4656;
        Nn = t2 / 96; Mm = t2 - Nn*96;
        XA = XSh + Nn*6144; XB = XTh + Mm*6144;
        dA = d0S + Nn*48;   dB = d0T + Mm*48;
        wA = wS  + Nn*48;   wB = zT  + Mm*48;
    }

    const int m = lane & 15, g = lane >> 4;

    // sigma = XA(48x128) . XB(48x128)^T via 3x3 tiles of mfma_f32_16x16x32_f16.
    // A and B fragments use the SAME (g,reg)->k bijection, so the k-contraction
    // is permutation-invariant -> layout-safe. C/D: row=(lane>>4)*4+reg, col=lane&15.
    f32x4 acc[3][3];
    #pragma unroll
    for (int i = 0; i < 3; ++i)
        #pragma unroll
        for (int j = 0; j < 3; ++j) acc[i][j] = (f32x4){0.f, 0.f, 0.f, 0.f};

    #pragma unroll
    for (int kk = 0; kk < 4; ++kk) {
        half8 af[3], bf[3];
        #pragma unroll
        for (int ti = 0; ti < 3; ++ti)
            af[ti] = *reinterpret_cast<const half8*>(XA + (ti*16 + m)*128 + kk*32 + g*8);
        #pragma unroll
        for (int tj = 0; tj < 3; ++tj)
            bf[tj] = *reinterpret_cast<const half8*>(XB + (tj*16 + m)*128 + kk*32 + g*8);
        #pragma unroll
        for (int ti = 0; ti < 3; ++ti)
            #pragma unroll
            for (int tj = 0; tj < 3; ++tj)
                acc[ti][tj] = __builtin_amdgcn_mfma_f32_16x16x32_f16(af[ti], bf[tj], acc[ti][tj], 0, 0, 0);
    }

    // second-layer diag closed form: d1 = d0 * sqrt(C1), C1 = S_next(0.9999)
    const float th0 = acosf(0.9999f);
    const float C1 = (0.9999f*(PI_F - th0) + sqrtf(1.f - 0.9999f*0.9999f)) / PI_F;
    const float sC1 = sqrtf(C1);

    float dB0v[3], dB1v[3], wBv[3];
    #pragma unroll
    for (int tj = 0; tj < 3; ++tj) {
        const float d = dB[tj*16 + m];
        dB0v[tj] = d; dB1v[tj] = d * sC1; wBv[tj] = wB[tj*16 + m];
    }

    float val = 0.f;
    #pragma unroll
    for (int ti = 0; ti < 3; ++ti) {
        #pragma unroll
        for (int r = 0; r < 4; ++r) {
            const int a = ti*16 + g*4 + r;
            const float da0 = dA[a];
            const float da1 = da0 * sC1;
            const float wa  = wA[a];
            #pragma unroll
            for (int tj = 0; tj < 3; ++tj) {
                float sig = acc[ti][tj][r] + 1e-4f;
                float ntkv = sig, s, ds;
                const float tmp0 = da0 * dB0v[tj] + 1e-6f;
                ntk_next(sig / tmp0, s, ds);
                ntkv = ntkv * ds + s;
                sig = s * tmp0;
                const float tmp1 = da1 * dB1v[tj] + 1e-6f;
                ntk_next(sig / tmp1, s, ds);
                ntkv = ntkv * ds + s;
                val += wa * ntkv * wBv[tj];
            }
        }
    }

    #pragma unroll
    for (int off = 32; off > 0; off >>= 1) val += __shfl_down(val, off);
    if (lane == 0) {
        if (isSS) {
            Kss[Nn*96 + Mm] = val;
            if (Mm != Nn) Kss[Mm*96 + Nn] = val;
        } else {
            Kst[Nn*96 + Mm] = val;
        }
    }
}

// ---------------- single-block: regularize, no-pivot GE (SPD), backsub, pred ----------------
__global__ __launch_bounds__(256) void solve_pred_kernel(
    const float* __restrict__ Kss, const float* __restrict__ yS,
    const float* __restrict__ Kst, float* __restrict__ pred)
{
    const int tid = threadIdx.x;
    const int LDA = 109;  // 109%32=13, gcd(13,32)=1 -> conflict-friendly column walks
    __shared__ float aug[96*109];
    __shared__ float rowfac[96];
    __shared__ float xk[10];
    __shared__ float red[4];
    __shared__ float lam;

    for (int idx = tid; idx < 96*96; idx += 256) aug[(idx/96)*LDA + (idx%96)] = Kss[idx];
    for (int idx = tid; idx < 960; idx += 256) aug[(idx/10)*LDA + 96 + (idx%10)] = yS[idx];
    __syncthreads();

    // lam = 1e-6 * trace / 96, parallel reduce
    {
        float v = (tid < 96) ? aug[tid*LDA + tid] : 0.f;
        #pragma unroll
        for (int off = 32; off > 0; off >>= 1) v += __shfl_down(v, off);
        if ((tid & 63) == 0) red[tid >> 6] = v;
        __syncthreads();
        if (tid == 0) lam = 1e-6f * (red[0] + red[1] + red[2] + red[3]) / 96.f;
        __syncthreads();
        if (tid < 96) aug[tid*LDA + tid] += lam;
        __syncthreads();
    }

    // forward elimination, no pivoting (K_SS + lam*I is SPD)
    const int er = tid >> 5, ec = tid & 31;   // 8 x 32
    for (int k = 0; k < 96; ++k) {
        if (tid > k && tid < 96) rowfac[tid] = aug[tid*LDA + k] / aug[k*LDA + k];
        __syncthreads();
        for (int i = k + 1 + er; i < 96; i += 8) {
            const float f = rowfac[i];
            for (int j = k + 1 + ec; j < 106; j += 32)
                aug[i*LDA + j] -= f * aug[k*LDA + j];
        }
        __syncthreads();
    }

    // back substitution (10 RHS)
    const int br = tid >> 4, bc = tid & 15;   // 16 x 16 (cols 10 used)
    for (int k = 95; k >= 0; --k) {
        if (tid < 10) {
            const float v = aug[k*LDA + 96 + tid] / aug[k*LDA + k];
            xk[tid] = v;
            aug[k*LDA + 96 + tid] = v;
        }
        __syncthreads();
        if (bc < 10) {
            for (int i = br; i < k; i += 16)
                aug[i*LDA + 96 + bc] -= aug[i*LDA + k] * xk[bc];
        }
        __syncthreads();
    }

    // pred = K_ST^T @ alpha
    for (int idx = tid; idx < 960; idx += 256) {
        const int t = idx / 10, c = idx % 10;
        float s = 0.f;
        for (int n = 0; n < 96; ++n) s += Kst[n*96 + t] * aug[n*LDA + 96 + c];
        pred[idx] = s;
    }
}

extern "C" void kernel_launch(void* const* d_in, const int* in_sizes, int n_in,
                              void* d_out, int out_size, void* d_ws, size_t ws_size,
                              hipStream_t stream)
{
    (void)in_sizes; (void)n_in; (void)out_size; (void)ws_size;
    const float* U_S = (const float*)d_in[0];
    const float* V_S = (const float*)d_in[1];
    const float* X_S = (const float*)d_in[2];
    const float* y_S = (const float*)d_in[3];
    const float* A_T = (const float*)d_in[4];
    const float* X_T = (const float*)d_in[5];

    float* out  = (float*)d_out;
    float* pred = out;         // (96,10)
    float* Kss  = out + 960;   // (96,96)

    float* ws  = (float*)d_ws;
    float* wS  = ws;                       // 96*48
    float* d0S = ws + 4608;                // 96*48
    float* d0T = ws + 9216;                // 96*48
    float* zT  = ws + 13824;               // 96*48
    float* Kst = ws + 18432;               // 96*96
    unsigned short* XSh = (unsigned short*)(ws + 27648);    // 96*48*128 f16
    unsigned short* XTh = XSh + 96*6144;                    // 96*48*128 f16

    precompute_kernel<<<96, 256, 0, stream>>>(U_S, V_S, X_S, X_T, A_T,
                                              wS, d0S, d0T, zT, XSh, XTh);
    pair_kernel<<<3468, 256, 0, stream>>>(XSh, XTh, d0S, d0T, wS, zT, Kss, Kst);
    solve_pred_kernel<<<1, 256, 0, stream>>>(Kss, y_S, Kst, pred);
}

// Round 8
// 286.261 us; speedup vs baseline: 2.7865x; 1.3112x over previous
//
#include <hip/hip_runtime.h>

#define PI_F    3.14159265358979323846f
#define INV_PI  0.31830988618379067154f

typedef _Float16 half8 __attribute__((ext_vector_type(8)));
typedef float f32x4 __attribute__((ext_vector_type(4)));

__device__ __forceinline__ unsigned short f2h_bits(float v) {
    union { _Float16 h; unsigned short u; } x; x.h = (_Float16)v; return x.u;
}
__device__ __forceinline__ float h2f(unsigned short u) {
    union { unsigned short u; _Float16 h; } x; x.u = u; return (float)x.h;
}

// fast ntk step: A&S 4.4.45 acos (abs err <= 6.7e-5) + v_sqrt + v_rcp.
// f16 sigma already contributes ~1e-3 rel; this approx adds ~2e-5 -> negligible.
__device__ __forceinline__ void ntk_next(float S, float& s_new, float& ds) {
    S = fminf(fmaxf(S, -0.9999f), 0.9999f);
    const float ax = __builtin_fabsf(S);
    const float t  = __builtin_amdgcn_sqrtf(1.0f - ax);
    float p = fmaf(ax, -0.0187293f, 0.0742610f);
    p = fmaf(ax, p, -0.2121144f);
    p = fmaf(ax, p, 1.5707288f);
    const float ac  = t * p;                       // acos(|S|)
    const float pmt = (S >= 0.f) ? (PI_F - ac) : ac;  // PI - acos(S)
    ds = pmt * INV_PI;
    const float root = __builtin_amdgcn_sqrtf(fmaf(-S, S, 1.0f));
    s_new = fmaf(S, pmt, root) * INV_PI;
}

// ---------------- per-graph precompute: w_S, z_T, f16(X), d0 from f16(X) ----------------
__global__ __launch_bounds__(256) void precompute_kernel(
    const float* __restrict__ U_S, const float* __restrict__ V_S,
    const float* __restrict__ X_S, const float* __restrict__ X_T,
    const float* __restrict__ A_T,
    float* __restrict__ wS, float* __restrict__ d0S,
    float* __restrict__ d0T, float* __restrict__ zT,
    unsigned short* __restrict__ XSh, unsigned short* __restrict__ XTh)
{
    const int g = blockIdx.x, tid = threadIdx.x;
    __shared__ float U[768], V[768], VU[256], VUp[256], t16[16], t2[16], r48[48];
    __shared__ unsigned int Xb[3072];

    for (int i = tid; i < 768; i += 256) { U[i] = U_S[g*768 + i]; V[i] = V_S[g*768 + i]; }
    __syncthreads();
    {   // VU = V(16x48) @ U(48x16)
        const int i = tid >> 4, j = tid & 15;
        float s = 0.f;
        #pragma unroll 4
        for (int k = 0; k < 48; ++k) s += V[i*48 + k] * U[k*16 + j];
        VU[tid] = s;
    }
    if (tid < 16) { float s = 0.f; for (int a = 0; a < 48; ++a) s += U[a*16 + tid]; t16[tid] = s; }
    __syncthreads();
    {   // VUp = VU @ VU
        const int i = tid >> 4, j = tid & 15;
        float s = 0.f;
        #pragma unroll
        for (int k = 0; k < 16; ++k) s += VU[i*16 + k] * VU[k*16 + j];
        VUp[tid] = s;
    }
    __syncthreads();
    if (tid < 16) { float s = 0.f; for (int b = 0; b < 16; ++b) s += t16[b] * VUp[b*16 + tid]; t2[tid] = s; }
    __syncthreads();
    if (tid < 48) { float s = 0.f; for (int b = 0; b < 16; ++b) s += t2[b] * V[b*48 + tid]; wS[g*48 + tid] = s; }

    // ---- X_S -> f16, d0S from rounded values ----
    for (int j = tid; j < 3072; j += 256) {
        const float2 xv = reinterpret_cast<const float2*>(X_S + g*6144)[j];
        const unsigned int u = (unsigned int)f2h_bits(xv.x) | ((unsigned int)f2h_bits(xv.y) << 16);
        Xb[j] = u;
        reinterpret_cast<unsigned int*>(XSh)[g*3072 + j] = u;
    }
    __syncthreads();
    if (tid < 48) {
        float s = 0.f;
        #pragma unroll 4
        for (int j = 0; j < 64; ++j) {
            const unsigned int u = Xb[tid*64 + j];
            const float lo = h2f((unsigned short)(u & 0xffffu));
            const float hi = h2f((unsigned short)(u >> 16));
            s += lo*lo + hi*hi;
        }
        d0S[g*48 + tid] = sqrtf(s + 1e-4f);
    }
    __syncthreads();
    // ---- X_T -> f16, d0T ----
    for (int j = tid; j < 3072; j += 256) {
        const float2 xv = reinterpret_cast<const float2*>(X_T + g*6144)[j];
        const unsigned int u = (unsigned int)f2h_bits(xv.x) | ((unsigned int)f2h_bits(xv.y) << 16);
        Xb[j] = u;
        reinterpret_cast<unsigned int*>(XTh)[g*3072 + j] = u;
    }
    __syncthreads();
    if (tid < 48) {
        float s = 0.f;
        #pragma unroll 4
        for (int j = 0; j < 64; ++j) {
            const unsigned int u = Xb[tid*64 + j];
            const float lo = h2f((unsigned short)(u & 0xffffu));
            const float hi = h2f((unsigned short)(u >> 16));
            s += lo*lo + hi*hi;
        }
        d0T[g*48 + tid] = sqrtf(s + 1e-4f);
    }

    // ---- z_T = A'^T (A'^T 1), A' = A + 1e-4 I ----
    if (tid < 48) {
        const float* A = A_T + g*2304;
        float rc = 0.f;
        for (int d = 0; d < 48; ++d) rc += A[d*48 + tid];
        r48[tid] = rc + 1e-4f;
    }
    __syncthreads();
    if (tid < 48) {
        const float* A = A_T + g*2304;
        float s = 0.f;
        for (int d = 0; d < 48; ++d) s += A[d*48 + tid] * r48[d];
        zT[g*48 + tid] = s + 1e-4f * r48[tid];
    }
}

// ---------------- pair kernel: one wave per (N,M) pair, MFMA f16 sigma ----------------
// pairs 0..4655: K_SS upper triangle (mirrored); 4656..13871: K_ST all pairs.
__global__ __launch_bounds__(256) void pair_kernel(
    const unsigned short* __restrict__ XSh, const unsigned short* __restrict__ XTh,
    const float* __restrict__ d0S, const float* __restrict__ d0T,
    const float* __restrict__ wS, const float* __restrict__ zT,
    float* __restrict__ Kss, float* __restrict__ Kst)
{
    const int wv = threadIdx.x >> 6, lane = threadIdx.x & 63;
    const int t = blockIdx.x * 4 + wv;
    if (t >= 13872) return;

    int Nn, Mm, isSS;
    const unsigned short *XA, *XB;
    const float *dA, *dB, *wA, *wB;
    if (t < 4656) {
        isSS = 1;
        int Ni = (int)((sqrtf(8.0f*(float)t + 1.0f) - 1.0f) * 0.5f);
        while (Ni*(Ni+1)/2 > t) --Ni;
        while ((Ni+1)*(Ni+2)/2 <= t) ++Ni;
        Nn = Ni; Mm = t - Ni*(Ni+1)/2;
        XA = XSh + Nn*6144; XB = XSh + Mm*6144;
        dA = d0S + Nn*48;   dB = d0S + Mm*48;
        wA = wS  + Nn*48;   wB = wS  + Mm*48;
    } else {
        isSS = 0;
        const int t2 = t - 4656;
        Nn = t2 / 96; Mm = t2 - Nn*96;
        XA = XSh + Nn*6144; XB = XTh + Mm*6144;
        dA = d0S + Nn*48;   dB = d0T + Mm*48;
        wA = wS  + Nn*48;   wB = zT  + Mm*48;
    }

    const int m = lane & 15, g = lane >> 4;

    // sigma = XA(48x128) . XB(48x128)^T via 3x3 tiles of mfma_f32_16x16x32_f16.
    // A and B fragments use the SAME (g,reg)->k bijection -> layout-safe.
    // C/D: row=(lane>>4)*4+reg, col=lane&15.
    f32x4 acc[3][3];
    #pragma unroll
    for (int i = 0; i < 3; ++i)
        #pragma unroll
        for (int j = 0; j < 3; ++j) acc[i][j] = (f32x4){0.f, 0.f, 0.f, 0.f};

    #pragma unroll
    for (int kk = 0; kk < 4; ++kk) {
        half8 af[3], bf[3];
        #pragma unroll
        for (int ti = 0; ti < 3; ++ti)
            af[ti] = *reinterpret_cast<const half8*>(XA + (ti*16 + m)*128 + kk*32 + g*8);
        #pragma unroll
        for (int tj = 0; tj < 3; ++tj)
            bf[tj] = *reinterpret_cast<const half8*>(XB + (tj*16 + m)*128 + kk*32 + g*8);
        #pragma unroll
        for (int ti = 0; ti < 3; ++ti)
            #pragma unroll
            for (int tj = 0; tj < 3; ++tj)
                acc[ti][tj] = __builtin_amdgcn_mfma_f32_16x16x32_f16(af[ti], bf[tj], acc[ti][tj], 0, 0, 0);
    }

    // second-layer diag closed form: d1 = d0 * sqrt(C1), C1 = S_next(0.9999)
    const float th0 = acosf(0.9999f);
    const float C1 = (0.9999f*(PI_F - th0) + sqrtf(1.f - 0.9999f*0.9999f)) / PI_F;
    const float sC1 = sqrtf(C1);

    float dB0v[3], dB1v[3], wBv[3];
    #pragma unroll
    for (int tj = 0; tj < 3; ++tj) {
        const float d = dB[tj*16 + m];
        dB0v[tj] = d; dB1v[tj] = d * sC1; wBv[tj] = wB[tj*16 + m];
    }

    float val = 0.f;
    #pragma unroll
    for (int ti = 0; ti < 3; ++ti) {
        #pragma unroll
        for (int r = 0; r < 4; ++r) {
            const int a = ti*16 + g*4 + r;
            const float da0 = dA[a];
            const float da1 = da0 * sC1;
            const float wa  = wA[a];
            #pragma unroll
            for (int tj = 0; tj < 3; ++tj) {
                float sig = acc[ti][tj][r] + 1e-4f;
                float ntkv = sig, s, ds;
                const float tmp0 = fmaf(da0, dB0v[tj], 1e-6f);
                ntk_next(sig * __builtin_amdgcn_rcpf(tmp0), s, ds);
                ntkv = fmaf(ntkv, ds, s);
                sig = s * tmp0;
                const float tmp1 = fmaf(da1, dB1v[tj], 1e-6f);
                ntk_next(sig * __builtin_amdgcn_rcpf(tmp1), s, ds);
                ntkv = fmaf(ntkv, ds, s);
                val = fmaf(wa * ntkv, wBv[tj], val);
            }
        }
    }

    #pragma unroll
    for (int off = 32; off > 0; off >>= 1) val += __shfl_down(val, off);
    if (lane == 0) {
        if (isSS) {
            Kss[Nn*96 + Mm] = val;
            if (Mm != Nn) Kss[Mm*96 + Nn] = val;
        } else {
            Kst[Nn*96 + Mm] = val;
        }
    }
}

// ---------------- single-block: regularize, no-pivot GE (SPD), backsub, pred ----------------
__global__ __launch_bounds__(256) void solve_pred_kernel(
    const float* __restrict__ Kss, const float* __restrict__ yS,
    const float* __restrict__ Kst, float* __restrict__ pred)
{
    const int tid = threadIdx.x;
    const int LDA = 109;  // 109%32=13, gcd(13,32)=1 -> conflict-friendly column walks
    __shared__ float aug[96*109];
    __shared__ float rowfac[96];
    __shared__ float xk[10];
    __shared__ float red[4];
    __shared__ float lam;

    for (int idx = tid; idx < 96*96; idx += 256) aug[(idx/96)*LDA + (idx%96)] = Kss[idx];
    for (int idx = tid; idx < 960; idx += 256) aug[(idx/10)*LDA + 96 + (idx%10)] = yS[idx];
    __syncthreads();

    // lam = 1e-6 * trace / 96, parallel reduce
    {
        float v = (tid < 96) ? aug[tid*LDA + tid] : 0.f;
        #pragma unroll
        for (int off = 32; off > 0; off >>= 1) v += __shfl_down(v, off);
        if ((tid & 63) == 0) red[tid >> 6] = v;
        __syncthreads();
        if (tid == 0) lam = 1e-6f * (red[0] + red[1] + red[2] + red[3]) / 96.f;
        __syncthreads();
        if (tid < 96) aug[tid*LDA + tid] += lam;
        __syncthreads();
    }

    // forward elimination, no pivoting (K_SS + lam*I is SPD)
    const int er = tid >> 5, ec = tid & 31;   // 8 x 32
    for (int k = 0; k < 95; ++k) {
        if (tid > k && tid < 96) rowfac[tid] = aug[tid*LDA + k] / aug[k*LDA + k];
        __syncthreads();
        // pivot-row element hoisted once per column; rowfac reads are LDS broadcasts
        for (int j = k + 1 + ec; j < 106; j += 32) {
            const float pv = aug[k*LDA + j];
            for (int i = k + 1 + er; i < 96; i += 8)
                aug[i*LDA + j] -= rowfac[i] * pv;
        }
        __syncthreads();
    }

    // back substitution (10 RHS)
    const int br = tid >> 4, bc = tid & 15;   // 16 x 16 (cols 10 used)
    for (int k = 95; k >= 0; --k) {
        if (tid < 10) {
            const float v = aug[k*LDA + 96 + tid] / aug[k*LDA + k];
            xk[tid] = v;
            aug[k*LDA + 96 + tid] = v;
        }
        __syncthreads();
        if (bc < 10) {
            for (int i = br; i < k; i += 16)
                aug[i*LDA + 96 + bc] -= aug[i*LDA + k] * xk[bc];
        }
        __syncthreads();
    }

    // pred = K_ST^T @ alpha
    for (int idx = tid; idx < 960; idx += 256) {
        const int t = idx / 10, c = idx % 10;
        float s = 0.f;
        for (int n = 0; n < 96; ++n) s += Kst[n*96 + t] * aug[n*LDA + 96 + c];
        pred[idx] = s;
    }
}

extern "C" void kernel_launch(void* const* d_in, const int* in_sizes, int n_in,
                              void* d_out, int out_size, void* d_ws, size_t ws_size,
                              hipStream_t stream)
{
    (void)in_sizes; (void)n_in; (void)out_size; (void)ws_size;
    const float* U_S = (const float*)d_in[0];
    const float* V_S = (const float*)d_in[1];
    const float* X_S = (const float*)d_in[2];
    const float* y_S = (const float*)d_in[3];
    const float* A_T = (const float*)d_in[4];
    const float* X_T = (const float*)d_in[5];

    float* out  = (float*)d_out;
    float* pred = out;         // (96,10)
    float* Kss  = out + 960;   // (96,96)

    float* ws  = (float*)d_ws;
    float* wS  = ws;                       // 96*48
    float* d0S = ws + 4608;                // 96*48
    float* d0T = ws + 9216;                // 96*48
    float* zT  = ws + 13824;               // 96*48
    float* Kst = ws + 18432;               // 96*96
    unsigned short* XSh = (unsigned short*)(ws + 27648);    // 96*48*128 f16
    unsigned short* XTh = XSh + 96*6144;                    // 96*48*128 f16

    precompute_kernel<<<96, 256, 0, stream>>>(U_S, V_S, X_S, X_T, A_T,
                                              wS, d0S, d0T, zT, XSh, XTh);
    pair_kernel<<<3468, 256, 0, stream>>>(XSh, XTh, d0S, d0T, wS, zT, Kss, Kst);
    solve_pred_kernel<<<1, 256, 0, stream>>>(Kss, y_S, Kst, pred);
}

// Round 11
// 256.082 us; speedup vs baseline: 3.1149x; 1.1178x over previous
//
#include <hip/hip_runtime.h>

#define PI_F    3.14159265358979323846f
#define INV_PI  0.31830988618379067154f

typedef _Float16 half8 __attribute__((ext_vector_type(8)));
typedef float f32x4 __attribute__((ext_vector_type(4)));

__device__ __forceinline__ unsigned short f2h_bits(float v) {
    union { _Float16 h; unsigned short u; } x; x.h = (_Float16)v; return x.u;
}
__device__ __forceinline__ float h2f(unsigned short u) {
    union { unsigned short u; _Float16 h; } x; x.u = u; return (float)x.h;
}

// fast ntk step: A&S 4.4.45 acos (abs err <= 6.7e-5) + v_sqrt + v_rcp.
__device__ __forceinline__ void ntk_next(float S, float& s_new, float& ds) {
    S = fminf(fmaxf(S, -0.9999f), 0.9999f);
    const float ax = __builtin_fabsf(S);
    const float t  = __builtin_amdgcn_sqrtf(1.0f - ax);
    float p = fmaf(ax, -0.0187293f, 0.0742610f);
    p = fmaf(ax, p, -0.2121144f);
    p = fmaf(ax, p, 1.5707288f);
    const float ac  = t * p;                       // acos(|S|)
    const float pmt = (S >= 0.f) ? (PI_F - ac) : ac;  // PI - acos(S)
    ds = pmt * INV_PI;
    const float root = __builtin_amdgcn_sqrtf(fmaf(-S, S, 1.0f));
    s_new = fmaf(S, pmt, root) * INV_PI;
}

// ---------------- per-graph precompute: w_S, z_T, f16(X), d0 from f16(X) ----------------
__global__ __launch_bounds__(256) void precompute_kernel(
    const float* __restrict__ U_S, const float* __restrict__ V_S,
    const float* __restrict__ X_S, const float* __restrict__ X_T,
    const float* __restrict__ A_T,
    float* __restrict__ wS, float* __restrict__ d0S,
    float* __restrict__ d0T, float* __restrict__ zT,
    unsigned short* __restrict__ XSh, unsigned short* __restrict__ XTh)
{
    const int g = blockIdx.x, tid = threadIdx.x;
    __shared__ float U[768], V[768], VU[256], VUp[256], t16[16], t2[16], r48[48];
    __shared__ unsigned int Xb[3072];

    for (int i = tid; i < 768; i += 256) { U[i] = U_S[g*768 + i]; V[i] = V_S[g*768 + i]; }
    __syncthreads();
    {   // VU = V(16x48) @ U(48x16)
        const int i = tid >> 4, j = tid & 15;
        float s = 0.f;
        #pragma unroll 4
        for (int k = 0; k < 48; ++k) s += V[i*48 + k] * U[k*16 + j];
        VU[tid] = s;
    }
    if (tid < 16) { float s = 0.f; for (int a = 0; a < 48; ++a) s += U[a*16 + tid]; t16[tid] = s; }
    __syncthreads();
    {   // VUp = VU @ VU
        const int i = tid >> 4, j = tid & 15;
        float s = 0.f;
        #pragma unroll
        for (int k = 0; k < 16; ++k) s += VU[i*16 + k] * VU[k*16 + j];
        VUp[tid] = s;
    }
    __syncthreads();
    if (tid < 16) { float s = 0.f; for (int b = 0; b < 16; ++b) s += t16[b] * VUp[b*16 + tid]; t2[tid] = s; }
    __syncthreads();
    if (tid < 48) { float s = 0.f; for (int b = 0; b < 16; ++b) s += t2[b] * V[b*48 + tid]; wS[g*48 + tid] = s; }

    // ---- X_S -> f16, d0S from rounded values ----
    for (int j = tid; j < 3072; j += 256) {
        const float2 xv = reinterpret_cast<const float2*>(X_S + g*6144)[j];
        const unsigned int u = (unsigned int)f2h_bits(xv.x) | ((unsigned int)f2h_bits(xv.y) << 16);
        Xb[j] = u;
        reinterpret_cast<unsigned int*>(XSh)[g*3072 + j] = u;
    }
    __syncthreads();
    if (tid < 48) {
        float s = 0.f;
        #pragma unroll 4
        for (int j = 0; j < 64; ++j) {
            const unsigned int u = Xb[tid*64 + j];
            const float lo = h2f((unsigned short)(u & 0xffffu));
            const float hi = h2f((unsigned short)(u >> 16));
            s += lo*lo + hi*hi;
        }
        d0S[g*48 + tid] = sqrtf(s + 1e-4f);
    }
    __syncthreads();
    // ---- X_T -> f16, d0T ----
    for (int j = tid; j < 3072; j += 256) {
        const float2 xv = reinterpret_cast<const float2*>(X_T + g*6144)[j];
        const unsigned int u = (unsigned int)f2h_bits(xv.x) | ((unsigned int)f2h_bits(xv.y) << 16);
        Xb[j] = u;
        reinterpret_cast<unsigned int*>(XTh)[g*3072 + j] = u;
    }
    __syncthreads();
    if (tid < 48) {
        float s = 0.f;
        #pragma unroll 4
        for (int j = 0; j < 64; ++j) {
            const unsigned int u = Xb[tid*64 + j];
            const float lo = h2f((unsigned short)(u & 0xffffu));
            const float hi = h2f((unsigned short)(u >> 16));
            s += lo*lo + hi*hi;
        }
        d0T[g*48 + tid] = sqrtf(s + 1e-4f);
    }

    // ---- z_T = A'^T (A'^T 1), A' = A + 1e-4 I ----
    if (tid < 48) {
        const float* A = A_T + g*2304;
        float rc = 0.f;
        for (int d = 0; d < 48; ++d) rc += A[d*48 + tid];
        r48[tid] = rc + 1e-4f;
    }
    __syncthreads();
    if (tid < 48) {
        const float* A = A_T + g*2304;
        float s = 0.f;
        for (int d = 0; d < 48; ++d) s += A[d*48 + tid] * r48[d];
        zT[g*48 + tid] = s + 1e-4f * r48[tid];
    }
}

// ---------------- pair kernel: one wave per (N,M) pair, MFMA f16 sigma ----------------
// pairs 0..4655: K_SS upper triangle (mirrored); 4656..13871: K_ST all pairs.
__global__ __launch_bounds__(256) void pair_kernel(
    const unsigned short* __restrict__ XSh, const unsigned short* __restrict__ XTh,
    const float* __restrict__ d0S, const float* __restrict__ d0T,
    const float* __restrict__ wS, const float* __restrict__ zT,
    float* __restrict__ Kss, float* __restrict__ Kst)
{
    const int wv = threadIdx.x >> 6, lane = threadIdx.x & 63;
    const int t = blockIdx.x * 4 + wv;
    if (t >= 13872) return;

    int Nn, Mm, isSS;
    const unsigned short *XA, *XB;
    const float *dA, *dB, *wA, *wB;
    if (t < 4656) {
        isSS = 1;
        int Ni = (int)((sqrtf(8.0f*(float)t + 1.0f) - 1.0f) * 0.5f);
        while (Ni*(Ni+1)/2 > t) --Ni;
        while ((Ni+1)*(Ni+2)/2 <= t) ++Ni;
        Nn = Ni; Mm = t - Ni*(Ni+1)/2;
        XA = XSh + Nn*6144; XB = XSh + Mm*6144;
        dA = d0S + Nn*48;   dB = d0S + Mm*48;
        wA = wS  + Nn*48;   wB = wS  + Mm*48;
    } else {
        isSS = 0;
        const int t2 = t - 4656;
        Nn = t2 / 96; Mm = t2 - Nn*96;
        XA = XSh + Nn*6144; XB = XTh + Mm*6144;
        dA = d0S + Nn*48;   dB = d0T + Mm*48;
        wA = wS  + Nn*48;   wB = zT  + Mm*48;
    }

    const int m = lane & 15, g = lane >> 4;

    // sigma = XA(48x128) . XB(48x128)^T via 3x3 tiles of mfma_f32_16x16x32_f16.
    // A and B fragments use the SAME (g,reg)->k bijection -> layout-safe.
    // C/D: row=(lane>>4)*4+reg, col=lane&15.
    f32x4 acc[3][3];
    #pragma unroll
    for (int i = 0; i < 3; ++i)
        #pragma unroll
        for (int j = 0; j < 3; ++j) acc[i][j] = (f32x4){0.f, 0.f, 0.f, 0.f};

    #pragma unroll
    for (int kk = 0; kk < 4; ++kk) {
        half8 af[3], bf[3];
        #pragma unroll
        for (int ti = 0; ti < 3; ++ti)
            af[ti] = *reinterpret_cast<const half8*>(XA + (ti*16 + m)*128 + kk*32 + g*8);
        #pragma unroll
        for (int tj = 0; tj < 3; ++tj)
            bf[tj] = *reinterpret_cast<const half8*>(XB + (tj*16 + m)*128 + kk*32 + g*8);
        #pragma unroll
        for (int ti = 0; ti < 3; ++ti)
            #pragma unroll
            for (int tj = 0; tj < 3; ++tj)
                acc[ti][tj] = __builtin_amdgcn_mfma_f32_16x16x32_f16(af[ti], bf[tj], acc[ti][tj], 0, 0, 0);
    }

    // second-layer diag closed form: d1 = d0 * sqrt(C1), C1 = S_next(0.9999)
    const float th0 = acosf(0.9999f);
    const float C1 = (0.9999f*(PI_F - th0) + sqrtf(1.f - 0.9999f*0.9999f)) / PI_F;
    const float sC1 = sqrtf(C1);

    float dB0v[3], dB1v[3], wBv[3];
    #pragma unroll
    for (int tj = 0; tj < 3; ++tj) {
        const float d = dB[tj*16 + m];
        dB0v[tj] = d; dB1v[tj] = d * sC1; wBv[tj] = wB[tj*16 + m];
    }

    float val = 0.f;
    #pragma unroll
    for (int ti = 0; ti < 3; ++ti) {
        #pragma unroll
        for (int r = 0; r < 4; ++r) {
            const int a = ti*16 + g*4 + r;
            const float da0 = dA[a];
            const float da1 = da0 * sC1;
            const float wa  = wA[a];
            #pragma unroll
            for (int tj = 0; tj < 3; ++tj) {
                float sig = acc[ti][tj][r] + 1e-4f;
                float ntkv = sig, s, ds;
                const float tmp0 = fmaf(da0, dB0v[tj], 1e-6f);
                ntk_next(sig * __builtin_amdgcn_rcpf(tmp0), s, ds);
                ntkv = fmaf(ntkv, ds, s);
                sig = s * tmp0;
                const float tmp1 = fmaf(da1, dB1v[tj], 1e-6f);
                ntk_next(sig * __builtin_amdgcn_rcpf(tmp1), s, ds);
                ntkv = fmaf(ntkv, ds, s);
                val = fmaf(wa * ntkv, wBv[tj], val);
            }
        }
    }

    #pragma unroll
    for (int off = 32; off > 0; off >>= 1) val += __shfl_down(val, off);
    if (lane == 0) {
        if (isSS) {
            Kss[Nn*96 + Mm] = val;
            if (Mm != Nn) Kss[Mm*96 + Nn] = val;
        } else {
            Kst[Nn*96 + Mm] = val;
        }
    }
}

// ---------------- single-block blocked LU (panel=8) + blocked backsub + pred ----------------
// Panel factorization: single wave, wave-coherent volatile LDS (same-wave DS ops are
// in-order) -> zero barriers for the 8 serial pivot steps. TRSM+rank-8 GEMM fused per
// column-thread with U in registers. 2 barriers per panel instead of 16.
__global__ __launch_bounds__(256) void solve_pred_kernel(
    const float* __restrict__ Kss, const float* __restrict__ yS,
    const float* __restrict__ Kst, float* __restrict__ pred)
{
    const int tid = threadIdx.x;
    const int lane = tid & 63;
    const int LDA = 109;  // 109%32=13, gcd(13,32)=1 -> conflict-friendly column walks
    __shared__ float aug[96*109];
    __shared__ float red[4];
    __shared__ float lam;

    for (int idx = tid; idx < 96*96; idx += 256) aug[(idx/96)*LDA + (idx%96)] = Kss[idx];
    for (int idx = tid; idx < 960; idx += 256) aug[(idx/10)*LDA + 96 + (idx%10)] = yS[idx];
    __syncthreads();

    // lam = 1e-6 * trace / 96, parallel reduce
    {
        float v = (tid < 96) ? aug[tid*LDA + tid] : 0.f;
        #pragma unroll
        for (int off = 32; off > 0; off >>= 1) v += __shfl_down(v, off);
        if ((tid & 63) == 0) red[tid >> 6] = v;
        __syncthreads();
        if (tid == 0) lam = 1e-6f * (red[0] + red[1] + red[2] + red[3]) / 96.f;
        __syncthreads();
        if (tid < 96) aug[tid*LDA + tid] += lam;
        __syncthreads();
    }

    // ---- blocked forward elimination (no pivoting; K_SS + lam*I is SPD) ----
    for (int kb = 0; kb < 96; kb += 8) {
        // panel factorization: wave 0 only, no barriers inside (wave-coherent LDS)
        if (tid < 64) {
            volatile float* va = aug;
            for (int kk = kb; kk < kb + 8; ++kk) {
                const float inv = 1.0f / va[kk*LDA + kk];
                for (int i = kk + 1 + lane; i < 96; i += 64) {
                    const float f = va[i*LDA + kk] * inv;
                    va[i*LDA + kk] = f;                       // store L factor in place
                    for (int j = kk + 1; j < kb + 8; ++j)     // panel columns only
                        va[i*LDA + j] -= f * va[kk*LDA + j];
                }
            }
        }
        __syncthreads();

        // TRSM (8 U-rows, in registers) + rank-8 GEMM, one trailing column per thread
        const int j = kb + 8 + tid;
        if (j < 106) {
            float u[8];
            #pragma unroll
            for (int mm = 0; mm < 8; ++mm) u[mm] = aug[(kb+mm)*LDA + j];
            #pragma unroll
            for (int kk = 1; kk < 8; ++kk)
                #pragma unroll
                for (int mm = 0; mm < 8; ++mm)
                    if (mm < kk) u[kk] -= aug[(kb+kk)*LDA + (kb+mm)] * u[mm];
            #pragma unroll
            for (int mm = 1; mm < 8; ++mm) aug[(kb+mm)*LDA + j] = u[mm];
            for (int i = kb + 8; i < 96; ++i) {
                float s = aug[i*LDA + j];
                #pragma unroll
                for (int mm = 0; mm < 8; ++mm)
                    s -= aug[i*LDA + (kb+mm)] * u[mm];        // L reads broadcast across lanes
                aug[i*LDA + j] = s;
            }
        }
        __syncthreads();
    }

    // ---- blocked back substitution (panel=8, 10 RHS) ----
    for (int pb = 88; pb >= 0; pb -= 8) {
        if (tid < 10) {   // in-register 8x8 upper-tri solve, one RHS column per thread
            const int c = 96 + tid;
            float x[8];
            #pragma unroll
            for (int mm = 0; mm < 8; ++mm) x[mm] = aug[(pb+mm)*LDA + c];
            #pragma unroll
            for (int kk = 7; kk >= 0; --kk) {
                float s = x[kk];
                #pragma unroll
                for (int mm = 0; mm < 8; ++mm)
                    if (mm > kk) s -= aug[(pb+kk)*LDA + (pb+mm)] * x[mm];
                x[kk] = s / aug[(pb+kk)*LDA + (pb+kk)];
            }
            #pragma unroll
            for (int mm = 0; mm < 8; ++mm) aug[(pb+mm)*LDA + c] = x[mm];
        }
        __syncthreads();
        if (tid < 250) {  // update rows above: rank-8
            const int c = 96 + (tid % 10);
            for (int i = tid / 10; i < pb; i += 25) {
                float s = aug[i*LDA + c];
                #pragma unroll
                for (int mm = 0; mm < 8; ++mm)
                    s -= aug[i*LDA + (pb+mm)] * aug[(pb+mm)*LDA + c];
                aug[i*LDA + c] = s;
            }
        }
        __syncthreads();
    }

    // ---- pred = K_ST^T @ alpha (alpha in aug cols 96..105) ----
    for (int idx = tid; idx < 960; idx += 256) {
        const int t = idx / 10, c = idx % 10;
        float s = 0.f;
        for (int n = 0; n < 96; ++n) s += Kst[n*96 + t] * aug[n*LDA + 96 + c];
        pred[idx] = s;
    }
}

extern "C" void kernel_launch(void* const* d_in, const int* in_sizes, int n_in,
                              void* d_out, int out_size, void* d_ws, size_t ws_size,
                              hipStream_t stream)
{
    (void)in_sizes; (void)n_in; (void)out_size; (void)ws_size;
    const float* U_S = (const float*)d_in[0];
    const float* V_S = (const float*)d_in[1];
    const float* X_S = (const float*)d_in[2];
    const float* y_S = (const float*)d_in[3];
    const float* A_T = (const float*)d_in[4];
    const float* X_T = (const float*)d_in[5];

    float* out  = (float*)d_out;
    float* pred = out;         // (96,10)
    float* Kss  = out + 960;   // (96,96)

    float* ws  = (float*)d_ws;
    float* wS  = ws;                       // 96*48
    float* d0S = ws + 4608;                // 96*48
    float* d0T = ws + 9216;                // 96*48
    float* zT  = ws + 13824;               // 96*48
    float* Kst = ws + 18432;               // 96*96
    unsigned short* XSh = (unsigned short*)(ws + 27648);    // 96*48*128 f16
    unsigned short* XTh = XSh + 96*6144;                    // 96*48*128 f16

    precompute_kernel<<<96, 256, 0, stream>>>(U_S, V_S, X_S, X_T, A_T,
                                              wS, d0S, d0T, zT, XSh, XTh);
    pair_kernel<<<3468, 256, 0, stream>>>(XSh, XTh, d0S, d0T, wS, zT, Kss, Kst);
    solve_pred_kernel<<<1, 256, 0, stream>>>(Kss, y_S, Kst, pred);
}

// Round 12
// 209.540 us; speedup vs baseline: 3.8067x; 1.2221x over previous
//
#include <hip/hip_runtime.h>

#define PI_F    3.14159265358979323846f
#define INV_PI  0.31830988618379067154f

typedef _Float16 half8 __attribute__((ext_vector_type(8)));
typedef float f32x4 __attribute__((ext_vector_type(4)));

__device__ __forceinline__ unsigned short f2h_bits(float v) {
    union { _Float16 h; unsigned short u; } x; x.h = (_Float16)v; return x.u;
}
__device__ __forceinline__ float h2f(unsigned short u) {
    union { unsigned short u; _Float16 h; } x; x.u = u; return (float)x.h;
}

// fast ntk step: A&S 4.4.45 acos (abs err <= 6.7e-5) + v_sqrt + v_rcp.
__device__ __forceinline__ void ntk_next(float S, float& s_new, float& ds) {
    S = fminf(fmaxf(S, -0.9999f), 0.9999f);
    const float ax = __builtin_fabsf(S);
    const float t  = __builtin_amdgcn_sqrtf(1.0f - ax);
    float p = fmaf(ax, -0.0187293f, 0.0742610f);
    p = fmaf(ax, p, -0.2121144f);
    p = fmaf(ax, p, 1.5707288f);
    const float ac  = t * p;                       // acos(|S|)
    const float pmt = (S >= 0.f) ? (PI_F - ac) : ac;  // PI - acos(S)
    ds = pmt * INV_PI;
    const float root = __builtin_amdgcn_sqrtf(fmaf(-S, S, 1.0f));
    s_new = fmaf(S, pmt, root) * INV_PI;
}

// ---------------- per-graph precompute: w_S, z_T, f16(X), d0 from f16(X) ----------------
__global__ __launch_bounds__(256) void precompute_kernel(
    const float* __restrict__ U_S, const float* __restrict__ V_S,
    const float* __restrict__ X_S, const float* __restrict__ X_T,
    const float* __restrict__ A_T,
    float* __restrict__ wS, float* __restrict__ d0S,
    float* __restrict__ d0T, float* __restrict__ zT,
    unsigned short* __restrict__ XSh, unsigned short* __restrict__ XTh)
{
    const int g = blockIdx.x, tid = threadIdx.x;
    __shared__ float U[768], V[768], VU[256], VUp[256], t16[16], t2[16], r48[48];
    __shared__ unsigned int Xb[3072];

    for (int i = tid; i < 768; i += 256) { U[i] = U_S[g*768 + i]; V[i] = V_S[g*768 + i]; }
    __syncthreads();
    {   // VU = V(16x48) @ U(48x16)
        const int i = tid >> 4, j = tid & 15;
        float s = 0.f;
        #pragma unroll 4
        for (int k = 0; k < 48; ++k) s += V[i*48 + k] * U[k*16 + j];
        VU[tid] = s;
    }
    if (tid < 16) { float s = 0.f; for (int a = 0; a < 48; ++a) s += U[a*16 + tid]; t16[tid] = s; }
    __syncthreads();
    {   // VUp = VU @ VU
        const int i = tid >> 4, j = tid & 15;
        float s = 0.f;
        #pragma unroll
        for (int k = 0; k < 16; ++k) s += VU[i*16 + k] * VU[k*16 + j];
        VUp[tid] = s;
    }
    __syncthreads();
    if (tid < 16) { float s = 0.f; for (int b = 0; b < 16; ++b) s += t16[b] * VUp[b*16 + tid]; t2[tid] = s; }
    __syncthreads();
    if (tid < 48) { float s = 0.f; for (int b = 0; b < 16; ++b) s += t2[b] * V[b*48 + tid]; wS[g*48 + tid] = s; }

    // ---- X_S -> f16, d0S from rounded values ----
    for (int j = tid; j < 3072; j += 256) {
        const float2 xv = reinterpret_cast<const float2*>(X_S + g*6144)[j];
        const unsigned int u = (unsigned int)f2h_bits(xv.x) | ((unsigned int)f2h_bits(xv.y) << 16);
        Xb[j] = u;
        reinterpret_cast<unsigned int*>(XSh)[g*3072 + j] = u;
    }
    __syncthreads();
    if (tid < 48) {
        float s = 0.f;
        #pragma unroll 4
        for (int j = 0; j < 64; ++j) {
            const unsigned int u = Xb[tid*64 + j];
            const float lo = h2f((unsigned short)(u & 0xffffu));
            const float hi = h2f((unsigned short)(u >> 16));
            s += lo*lo + hi*hi;
        }
        d0S[g*48 + tid] = sqrtf(s + 1e-4f);
    }
    __syncthreads();
    // ---- X_T -> f16, d0T ----
    for (int j = tid; j < 3072; j += 256) {
        const float2 xv = reinterpret_cast<const float2*>(X_T + g*6144)[j];
        const unsigned int u = (unsigned int)f2h_bits(xv.x) | ((unsigned int)f2h_bits(xv.y) << 16);
        Xb[j] = u;
        reinterpret_cast<unsigned int*>(XTh)[g*3072 + j] = u;
    }
    __syncthreads();
    if (tid < 48) {
        float s = 0.f;
        #pragma unroll 4
        for (int j = 0; j < 64; ++j) {
            const unsigned int u = Xb[tid*64 + j];
            const float lo = h2f((unsigned short)(u & 0xffffu));
            const float hi = h2f((unsigned short)(u >> 16));
            s += lo*lo + hi*hi;
        }
        d0T[g*48 + tid] = sqrtf(s + 1e-4f);
    }

    // ---- z_T = A'^T (A'^T 1), A' = A + 1e-4 I ----
    if (tid < 48) {
        const float* A = A_T + g*2304;
        float rc = 0.f;
        for (int d = 0; d < 48; ++d) rc += A[d*48 + tid];
        r48[tid] = rc + 1e-4f;
    }
    __syncthreads();
    if (tid < 48) {
        const float* A = A_T + g*2304;
        float s = 0.f;
        for (int d = 0; d < 48; ++d) s += A[d*48 + tid] * r48[d];
        zT[g*48 + tid] = s + 1e-4f * r48[tid];
    }
}

// ---------------- pair kernel: one wave per (N,M) pair, MFMA f16 sigma ----------------
// pairs 0..4655: K_SS upper triangle (mirrored); 4656..13871: K_ST all pairs.
__global__ __launch_bounds__(256) void pair_kernel(
    const unsigned short* __restrict__ XSh, const unsigned short* __restrict__ XTh,
    const float* __restrict__ d0S, const float* __restrict__ d0T,
    const float* __restrict__ wS, const float* __restrict__ zT,
    float* __restrict__ Kss, float* __restrict__ Kst)
{
    const int wv = threadIdx.x >> 6, lane = threadIdx.x & 63;
    const int t = blockIdx.x * 4 + wv;
    if (t >= 13872) return;

    int Nn, Mm, isSS;
    const unsigned short *XA, *XB;
    const float *dA, *dB, *wA, *wB;
    if (t < 4656) {
        isSS = 1;
        int Ni = (int)((sqrtf(8.0f*(float)t + 1.0f) - 1.0f) * 0.5f);
        while (Ni*(Ni+1)/2 > t) --Ni;
        while ((Ni+1)*(Ni+2)/2 <= t) ++Ni;
        Nn = Ni; Mm = t - Ni*(Ni+1)/2;
        XA = XSh + Nn*6144; XB = XSh + Mm*6144;
        dA = d0S + Nn*48;   dB = d0S + Mm*48;
        wA = wS  + Nn*48;   wB = wS  + Mm*48;
    } else {
        isSS = 0;
        const int t2 = t - 4656;
        Nn = t2 / 96; Mm = t2 - Nn*96;
        XA = XSh + Nn*6144; XB = XTh + Mm*6144;
        dA = d0S + Nn*48;   dB = d0T + Mm*48;
        wA = wS  + Nn*48;   wB = zT  + Mm*48;
    }

    const int m = lane & 15, g = lane >> 4;

    // sigma = XA(48x128) . XB(48x128)^T via 3x3 tiles of mfma_f32_16x16x32_f16.
    // A and B fragments use the SAME (g,reg)->k bijection -> layout-safe.
    // C/D: row=(lane>>4)*4+reg, col=lane&15.
    f32x4 acc[3][3];
    #pragma unroll
    for (int i = 0; i < 3; ++i)
        #pragma unroll
        for (int j = 0; j < 3; ++j) acc[i][j] = (f32x4){0.f, 0.f, 0.f, 0.f};

    #pragma unroll
    for (int kk = 0; kk < 4; ++kk) {
        half8 af[3], bf[3];
        #pragma unroll
        for (int ti = 0; ti < 3; ++ti)
            af[ti] = *reinterpret_cast<const half8*>(XA + (ti*16 + m)*128 + kk*32 + g*8);
        #pragma unroll
        for (int tj = 0; tj < 3; ++tj)
            bf[tj] = *reinterpret_cast<const half8*>(XB + (tj*16 + m)*128 + kk*32 + g*8);
        #pragma unroll
        for (int ti = 0; ti < 3; ++ti)
            #pragma unroll
            for (int tj = 0; tj < 3; ++tj)
                acc[ti][tj] = __builtin_amdgcn_mfma_f32_16x16x32_f16(af[ti], bf[tj], acc[ti][tj], 0, 0, 0);
    }

    // second-layer diag closed form: d1 = d0 * sqrt(C1), C1 = S_next(0.9999)
    const float th0 = acosf(0.9999f);
    const float C1 = (0.9999f*(PI_F - th0) + sqrtf(1.f - 0.9999f*0.9999f)) / PI_F;
    const float sC1 = sqrtf(C1);

    float dB0v[3], dB1v[3], wBv[3];
    #pragma unroll
    for (int tj = 0; tj < 3; ++tj) {
        const float d = dB[tj*16 + m];
        dB0v[tj] = d; dB1v[tj] = d * sC1; wBv[tj] = wB[tj*16 + m];
    }

    float val = 0.f;
    #pragma unroll
    for (int ti = 0; ti < 3; ++ti) {
        #pragma unroll
        for (int r = 0; r < 4; ++r) {
            const int a = ti*16 + g*4 + r;
            const float da0 = dA[a];
            const float da1 = da0 * sC1;
            const float wa  = wA[a];
            #pragma unroll
            for (int tj = 0; tj < 3; ++tj) {
                float sig = acc[ti][tj][r] + 1e-4f;
                float ntkv = sig, s, ds;
                const float tmp0 = fmaf(da0, dB0v[tj], 1e-6f);
                ntk_next(sig * __builtin_amdgcn_rcpf(tmp0), s, ds);
                ntkv = fmaf(ntkv, ds, s);
                sig = s * tmp0;
                const float tmp1 = fmaf(da1, dB1v[tj], 1e-6f);
                ntk_next(sig * __builtin_amdgcn_rcpf(tmp1), s, ds);
                ntkv = fmaf(ntkv, ds, s);
                val = fmaf(wa * ntkv, wBv[tj], val);
            }
        }
    }

    #pragma unroll
    for (int off = 32; off > 0; off >>= 1) val += __shfl_down(val, off);
    if (lane == 0) {
        if (isSS) {
            Kss[Nn*96 + Mm] = val;
            if (Mm != Nn) Kss[Mm*96 + Nn] = val;
        } else {
            Kst[Nn*96 + Mm] = val;
        }
    }
}

// ---------------- single-block blocked LU: register panel + shuffle broadcast ----------------
// Panel (96x8) lives in wave-0 registers (lane owns rows lane, lane+64); pivot rows are
// broadcast via __shfl -> the serial path never touches LDS. TRSM per trailing column,
// then 2D rank-8 GEMM (2 row-groups x 128 cols, 4 active waves, L reads are broadcasts).
__global__ __launch_bounds__(256) void solve_pred_kernel(
    const float* __restrict__ Kss, const float* __restrict__ yS,
    const float* __restrict__ Kst, float* __restrict__ pred)
{
    const int tid = threadIdx.x;
    const int lane = tid & 63;
    const int LDA = 109;  // 109%32=13, gcd(13,32)=1 -> conflict-friendly column walks
    __shared__ float aug[96*109];
    __shared__ float red[4];
    __shared__ float lam;

    for (int idx = tid; idx < 96*96; idx += 256) aug[(idx/96)*LDA + (idx%96)] = Kss[idx];
    for (int idx = tid; idx < 960; idx += 256) aug[(idx/10)*LDA + 96 + (idx%10)] = yS[idx];
    __syncthreads();

    // lam = 1e-6 * trace / 96, parallel reduce
    {
        float v = (tid < 96) ? aug[tid*LDA + tid] : 0.f;
        #pragma unroll
        for (int off = 32; off > 0; off >>= 1) v += __shfl_down(v, off);
        if ((tid & 63) == 0) red[tid >> 6] = v;
        __syncthreads();
        if (tid == 0) lam = 1e-6f * (red[0] + red[1] + red[2] + red[3]) / 96.f;
        __syncthreads();
        if (tid < 96) aug[tid*LDA + tid] += lam;
        __syncthreads();
    }

    // ---- blocked forward elimination (no pivoting; K_SS + lam*I is SPD) ----
    for (int kb = 0; kb < 96; kb += 8) {
        // panel factorization in registers on wave 0; pivot rows via shuffle broadcast
        if (tid < 64) {
            const int rA = lane, rB = lane + 64;
            const bool aAct = (rA >= kb);
            const bool bAct = (rB < 96) && (rB >= kb);
            float ra[8], rb[8], pv[8];
            #pragma unroll
            for (int m = 0; m < 8; ++m) {
                ra[m] = aAct ? aug[rA*LDA + kb + m] : 0.f;
                rb[m] = bAct ? aug[rB*LDA + kb + m] : 0.f;
            }
            #pragma unroll
            for (int kk = 0; kk < 8; ++kk) {
                const int pr = kb + kk;           // global pivot row (uniform)
                if (pr < 64) {
                    #pragma unroll
                    for (int m = 0; m < 8; ++m) pv[m] = __shfl(ra[m], pr);
                } else {
                    #pragma unroll
                    for (int m = 0; m < 8; ++m) pv[m] = __shfl(rb[m], pr - 64);
                }
                const float inv = 1.0f / pv[kk];
                if (aAct && rA > pr) {
                    const float f = ra[kk] * inv; ra[kk] = f;
                    #pragma unroll
                    for (int m = 0; m < 8; ++m) if (m > kk) ra[m] = fmaf(-f, pv[m], ra[m]);
                }
                if (bAct && rB > pr) {
                    const float f = rb[kk] * inv; rb[kk] = f;
                    #pragma unroll
                    for (int m = 0; m < 8; ++m) if (m > kk) rb[m] = fmaf(-f, pv[m], rb[m]);
                }
            }
            #pragma unroll
            for (int m = 0; m < 8; ++m) {
                if (aAct) aug[rA*LDA + kb + m] = ra[m];
                if (bAct) aug[rB*LDA + kb + m] = rb[m];
            }
        }
        __syncthreads();

        // TRSM: L8x8 * u = raw for each trailing column (one col per thread)
        const int j = kb + 8 + tid;
        if (j < 106) {
            float u[8];
            #pragma unroll
            for (int m = 0; m < 8; ++m) u[m] = aug[(kb+m)*LDA + j];
            #pragma unroll
            for (int kk = 1; kk < 8; ++kk)
                #pragma unroll
                for (int m = 0; m < 8; ++m)
                    if (m < kk) u[kk] -= aug[(kb+kk)*LDA + (kb+m)] * u[m];
            #pragma unroll
            for (int m = 1; m < 8; ++m) aug[(kb+m)*LDA + j] = u[m];
        }
        __syncthreads();

        // rank-8 GEMM: 2 row-groups x 128 cols (4 active waves); L reads wave-uniform
        {
            const int g2 = tid >> 7, cl = tid & 127;
            const int jc = kb + 8 + cl;
            const bool act = (jc < 106);
            float u[8];
            #pragma unroll
            for (int m = 0; m < 8; ++m) u[m] = act ? aug[(kb+m)*LDA + jc] : 0.f;
            for (int i = kb + 8 + g2; i < 96; i += 2) {
                float L[8];
                #pragma unroll
                for (int m = 0; m < 8; ++m) L[m] = aug[i*LDA + kb + m];  // broadcast
                if (act) {
                    float s = aug[i*LDA + jc];
                    #pragma unroll
                    for (int m = 0; m < 8; ++m) s = fmaf(-L[m], u[m], s);
                    aug[i*LDA + jc] = s;
                }
            }
        }
        __syncthreads();
    }

    // ---- blocked back substitution (panel=8, 10 RHS) ----
    for (int pb = 88; pb >= 0; pb -= 8) {
        if (tid < 10) {   // in-register 8x8 upper-tri solve, one RHS column per thread
            const int c = 96 + tid;
            float x[8];
            #pragma unroll
            for (int mm = 0; mm < 8; ++mm) x[mm] = aug[(pb+mm)*LDA + c];
            #pragma unroll
            for (int kk = 7; kk >= 0; --kk) {
                float s = x[kk];
                #pragma unroll
                for (int mm = 0; mm < 8; ++mm)
                    if (mm > kk) s -= aug[(pb+kk)*LDA + (pb+mm)] * x[mm];
                x[kk] = s / aug[(pb+kk)*LDA + (pb+kk)];
            }
            #pragma unroll
            for (int mm = 0; mm < 8; ++mm) aug[(pb+mm)*LDA + c] = x[mm];
        }
        __syncthreads();
        if (tid < 250) {  // update rows above: rank-8
            const int c = 96 + (tid % 10);
            for (int i = tid / 10; i < pb; i += 25) {
                float s = aug[i*LDA + c];
                #pragma unroll
                for (int mm = 0; mm < 8; ++mm)
                    s -= aug[i*LDA + (pb+mm)] * aug[(pb+mm)*LDA + c];
                aug[i*LDA + c] = s;
            }
        }
        __syncthreads();
    }

    // ---- pred = K_ST^T @ alpha (alpha in aug cols 96..105) ----
    for (int idx = tid; idx < 960; idx += 256) {
        const int t = idx / 10, c = idx % 10;
        float s = 0.f;
        for (int n = 0; n < 96; ++n) s += Kst[n*96 + t] * aug[n*LDA + 96 + c];
        pred[idx] = s;
    }
}

extern "C" void kernel_launch(void* const* d_in, const int* in_sizes, int n_in,
                              void* d_out, int out_size, void* d_ws, size_t ws_size,
                              hipStream_t stream)
{
    (void)in_sizes; (void)n_in; (void)out_size; (void)ws_size;
    const float* U_S = (const float*)d_in[0];
    const float* V_S = (const float*)d_in[1];
    const float* X_S = (const float*)d_in[2];
    const float* y_S = (const float*)d_in[3];
    const float* A_T = (const float*)d_in[4];
    const float* X_T = (const float*)d_in[5];

    float* out  = (float*)d_out;
    float* pred = out;         // (96,10)
    float* Kss  = out + 960;   // (96,96)

    float* ws  = (float*)d_ws;
    float* wS  = ws;                       // 96*48
    float* d0S = ws + 4608;                // 96*48
    float* d0T = ws + 9216;                // 96*48
    float* zT  = ws + 13824;               // 96*48
    float* Kst = ws + 18432;               // 96*96
    unsigned short* XSh = (unsigned short*)(ws + 27648);    // 96*48*128 f16
    unsigned short* XTh = XSh + 96*6144;                    // 96*48*128 f16

    precompute_kernel<<<96, 256, 0, stream>>>(U_S, V_S, X_S, X_T, A_T,
                                              wS, d0S, d0T, zT, XSh, XTh);
    pair_kernel<<<3468, 256, 0, stream>>>(XSh, XTh, d0S, d0T, wS, zT, Kss, Kst);
    solve_pred_kernel<<<1, 256, 0, stream>>>(Kss, y_S, Kst, pred);
}

// Round 15
// 191.811 us; speedup vs baseline: 4.1586x; 1.0924x over previous
//
#include <hip/hip_runtime.h>

#define PI_F    3.14159265358979323846f
#define INV_PI  0.31830988618379067154f

typedef _Float16 half8 __attribute__((ext_vector_type(8)));
typedef float f32x4 __attribute__((ext_vector_type(4)));

__device__ __forceinline__ unsigned short f2h_bits(float v) {
    union { _Float16 h; unsigned short u; } x; x.h = (_Float16)v; return x.u;
}
__device__ __forceinline__ float h2f(unsigned short u) {
    union { unsigned short u; _Float16 h; } x; x.u = u; return (float)x.h;
}

// fast ntk step: A&S 4.4.45 acos (abs err <= 6.7e-5) + v_sqrt + v_rcp.
__device__ __forceinline__ void ntk_next(float S, float& s_new, float& ds) {
    S = fminf(fmaxf(S, -0.9999f), 0.9999f);
    const float ax = __builtin_fabsf(S);
    const float t  = __builtin_amdgcn_sqrtf(1.0f - ax);
    float p = fmaf(ax, -0.0187293f, 0.0742610f);
    p = fmaf(ax, p, -0.2121144f);
    p = fmaf(ax, p, 1.5707288f);
    const float ac  = t * p;                       // acos(|S|)
    const float pmt = (S >= 0.f) ? (PI_F - ac) : ac;  // PI - acos(S)
    ds = pmt * INV_PI;
    const float root = __builtin_amdgcn_sqrtf(fmaf(-S, S, 1.0f));
    s_new = fmaf(S, pmt, root) * INV_PI;
}

// ---------------- per-graph precompute: w_S, z_T, f16(X), d0 from f16(X) ----------------
__global__ __launch_bounds__(256) void precompute_kernel(
    const float* __restrict__ U_S, const float* __restrict__ V_S,
    const float* __restrict__ X_S, const float* __restrict__ X_T,
    const float* __restrict__ A_T,
    float* __restrict__ wS, float* __restrict__ d0S,
    float* __restrict__ d0T, float* __restrict__ zT,
    unsigned short* __restrict__ XSh, unsigned short* __restrict__ XTh)
{
    const int g = blockIdx.x, tid = threadIdx.x;
    __shared__ float U[768], V[768], VU[256], VUp[256], t16[16], t2[16], r48[48];
    __shared__ unsigned int Xb[3072];

    for (int i = tid; i < 768; i += 256) { U[i] = U_S[g*768 + i]; V[i] = V_S[g*768 + i]; }
    __syncthreads();
    {   // VU = V(16x48) @ U(48x16)
        const int i = tid >> 4, j = tid & 15;
        float s = 0.f;
        #pragma unroll 4
        for (int k = 0; k < 48; ++k) s += V[i*48 + k] * U[k*16 + j];
        VU[tid] = s;
    }
    if (tid < 16) { float s = 0.f; for (int a = 0; a < 48; ++a) s += U[a*16 + tid]; t16[tid] = s; }
    __syncthreads();
    {   // VUp = VU @ VU
        const int i = tid >> 4, j = tid & 15;
        float s = 0.f;
        #pragma unroll
        for (int k = 0; k < 16; ++k) s += VU[i*16 + k] * VU[k*16 + j];
        VUp[tid] = s;
    }
    __syncthreads();
    if (tid < 16) { float s = 0.f; for (int b = 0; b < 16; ++b) s += t16[b] * VUp[b*16 + tid]; t2[tid] = s; }
    __syncthreads();
    if (tid < 48) { float s = 0.f; for (int b = 0; b < 16; ++b) s += t2[b] * V[b*48 + tid]; wS[g*48 + tid] = s; }

    // ---- X_S -> f16, d0S from rounded values ----
    for (int j = tid; j < 3072; j += 256) {
        const float2 xv = reinterpret_cast<const float2*>(X_S + g*6144)[j];
        const unsigned int u = (unsigned int)f2h_bits(xv.x) | ((unsigned int)f2h_bits(xv.y) << 16);
        Xb[j] = u;
        reinterpret_cast<unsigned int*>(XSh)[g*3072 + j] = u;
    }
    __syncthreads();
    if (tid < 48) {
        float s = 0.f;
        #pragma unroll 4
        for (int j = 0; j < 64; ++j) {
            const unsigned int u = Xb[tid*64 + j];
            const float lo = h2f((unsigned short)(u & 0xffffu));
            const float hi = h2f((unsigned short)(u >> 16));
            s += lo*lo + hi*hi;
        }
        d0S[g*48 + tid] = sqrtf(s + 1e-4f);
    }
    __syncthreads();
    // ---- X_T -> f16, d0T ----
    for (int j = tid; j < 3072; j += 256) {
        const float2 xv = reinterpret_cast<const float2*>(X_T + g*6144)[j];
        const unsigned int u = (unsigned int)f2h_bits(xv.x) | ((unsigned int)f2h_bits(xv.y) << 16);
        Xb[j] = u;
        reinterpret_cast<unsigned int*>(XTh)[g*3072 + j] = u;
    }
    __syncthreads();
    if (tid < 48) {
        float s = 0.f;
        #pragma unroll 4
        for (int j = 0; j < 64; ++j) {
            const unsigned int u = Xb[tid*64 + j];
            const float lo = h2f((unsigned short)(u & 0xffffu));
            const float hi = h2f((unsigned short)(u >> 16));
            s += lo*lo + hi*hi;
        }
        d0T[g*48 + tid] = sqrtf(s + 1e-4f);
    }

    // ---- z_T = A'^T (A'^T 1), A' = A + 1e-4 I ----
    if (tid < 48) {
        const float* A = A_T + g*2304;
        float rc = 0.f;
        for (int d = 0; d < 48; ++d) rc += A[d*48 + tid];
        r48[tid] = rc + 1e-4f;
    }
    __syncthreads();
    if (tid < 48) {
        const float* A = A_T + g*2304;
        float s = 0.f;
        for (int d = 0; d < 48; ++d) s += A[d*48 + tid] * r48[d];
        zT[g*48 + tid] = s + 1e-4f * r48[tid];
    }
}

// ---------------- pair kernel: one wave per (N,M) pair, MFMA f16 sigma ----------------
// pairs 0..4655: K_SS upper triangle (mirrored); 4656..13871: K_ST all pairs.
__global__ __launch_bounds__(256) void pair_kernel(
    const unsigned short* __restrict__ XSh, const unsigned short* __restrict__ XTh,
    const float* __restrict__ d0S, const float* __restrict__ d0T,
    const float* __restrict__ wS, const float* __restrict__ zT,
    float* __restrict__ Kss, float* __restrict__ Kst)
{
    const int wv = threadIdx.x >> 6, lane = threadIdx.x & 63;
    const int t = blockIdx.x * 4 + wv;
    if (t >= 13872) return;

    int Nn, Mm, isSS;
    const unsigned short *XA, *XB;
    const float *dA, *dB, *wA, *wB;
    if (t < 4656) {
        isSS = 1;
        int Ni = (int)((sqrtf(8.0f*(float)t + 1.0f) - 1.0f) * 0.5f);
        while (Ni*(Ni+1)/2 > t) --Ni;
        while ((Ni+1)*(Ni+2)/2 <= t) ++Ni;
        Nn = Ni; Mm = t - Ni*(Ni+1)/2;
        XA = XSh + Nn*6144; XB = XSh + Mm*6144;
        dA = d0S + Nn*48;   dB = d0S + Mm*48;
        wA = wS  + Nn*48;   wB = wS  + Mm*48;
    } else {
        isSS = 0;
        const int t2 = t - 4656;
        Nn = t2 / 96; Mm = t2 - Nn*96;
        XA = XSh + Nn*6144; XB = XTh + Mm*6144;
        dA = d0S + Nn*48;   dB = d0T + Mm*48;
        wA = wS  + Nn*48;   wB = zT  + Mm*48;
    }

    const int m = lane & 15, g = lane >> 4;

    // sigma = XA(48x128) . XB(48x128)^T via 3x3 tiles of mfma_f32_16x16x32_f16.
    // A and B fragments use the SAME (g,reg)->k bijection -> layout-safe.
    // C/D: row=(lane>>4)*4+reg, col=lane&15.
    f32x4 acc[3][3];
    #pragma unroll
    for (int i = 0; i < 3; ++i)
        #pragma unroll
        for (int j = 0; j < 3; ++j) acc[i][j] = (f32x4){0.f, 0.f, 0.f, 0.f};

    #pragma unroll
    for (int kk = 0; kk < 4; ++kk) {
        half8 af[3], bf[3];
        #pragma unroll
        for (int ti = 0; ti < 3; ++ti)
            af[ti] = *reinterpret_cast<const half8*>(XA + (ti*16 + m)*128 + kk*32 + g*8);
        #pragma unroll
        for (int tj = 0; tj < 3; ++tj)
            bf[tj] = *reinterpret_cast<const half8*>(XB + (tj*16 + m)*128 + kk*32 + g*8);
        #pragma unroll
        for (int ti = 0; ti < 3; ++ti)
            #pragma unroll
            for (int tj = 0; tj < 3; ++tj)
                acc[ti][tj] = __builtin_amdgcn_mfma_f32_16x16x32_f16(af[ti], bf[tj], acc[ti][tj], 0, 0, 0);
    }

    // second-layer diag closed form: d1 = d0 * sqrt(C1), C1 = S_next(0.9999)
    const float th0 = acosf(0.9999f);
    const float C1 = (0.9999f*(PI_F - th0) + sqrtf(1.f - 0.9999f*0.9999f)) / PI_F;
    const float sC1 = sqrtf(C1);

    float dB0v[3], dB1v[3], wBv[3];
    #pragma unroll
    for (int tj = 0; tj < 3; ++tj) {
        const float d = dB[tj*16 + m];
        dB0v[tj] = d; dB1v[tj] = d * sC1; wBv[tj] = wB[tj*16 + m];
    }

    float val = 0.f;
    #pragma unroll
    for (int ti = 0; ti < 3; ++ti) {
        #pragma unroll
        for (int r = 0; r < 4; ++r) {
            const int a = ti*16 + g*4 + r;
            const float da0 = dA[a];
            const float da1 = da0 * sC1;
            const float wa  = wA[a];
            #pragma unroll
            for (int tj = 0; tj < 3; ++tj) {
                float sig = acc[ti][tj][r] + 1e-4f;
                float ntkv = sig, s, ds;
                const float tmp0 = fmaf(da0, dB0v[tj], 1e-6f);
                ntk_next(sig * __builtin_amdgcn_rcpf(tmp0), s, ds);
                ntkv = fmaf(ntkv, ds, s);
                sig = s * tmp0;
                const float tmp1 = fmaf(da1, dB1v[tj], 1e-6f);
                ntk_next(sig * __builtin_amdgcn_rcpf(tmp1), s, ds);
                ntkv = fmaf(ntkv, ds, s);
                val = fmaf(wa * ntkv, wBv[tj], val);
            }
        }
    }

    #pragma unroll
    for (int off = 32; off > 0; off >>= 1) val += __shfl_down(val, off);
    if (lane == 0) {
        if (isSS) {
            Kss[Nn*96 + Mm] = val;
            if (Mm != Nn) Kss[Mm*96 + Nn] = val;
        } else {
            Kst[Nn*96 + Mm] = val;
        }
    }
}

// ---------------- single-block blocked LU: 512 threads, panel=16, register panel ----------------
// Panel (96x16) in wave-0 registers (lane owns rows lane, lane+64); pivot rows broadcast
// via __shfl (no LDS in the serial path). TRSM per trailing column; rank-16 GEMM on
// 4 row-groups x 128 cols (8 waves). 3 barriers per panel x 6 panels.
__global__ __launch_bounds__(512) void solve_pred_kernel(
    const float* __restrict__ Kss, const float* __restrict__ yS,
    const float* __restrict__ Kst, float* __restrict__ pred)
{
    const int tid = threadIdx.x;
    const int lane = tid & 63;
    const int LDA = 109;  // 109%32=13, gcd(13,32)=1 -> conflict-friendly column walks
    __shared__ float aug[96*109];
    __shared__ float red[8];
    __shared__ float lam;

    for (int idx = tid; idx < 96*96; idx += 512) aug[(idx/96)*LDA + (idx%96)] = Kss[idx];
    for (int idx = tid; idx < 960; idx += 512) aug[(idx/10)*LDA + 96 + (idx%10)] = yS[idx];
    __syncthreads();

    // lam = 1e-6 * trace / 96, parallel reduce
    {
        float v = (tid < 96) ? aug[tid*LDA + tid] : 0.f;
        #pragma unroll
        for (int off = 32; off > 0; off >>= 1) v += __shfl_down(v, off);
        if (lane == 0) red[tid >> 6] = v;
        __syncthreads();
        if (tid == 0) {
            float s = 0.f;
            #pragma unroll
            for (int w = 0; w < 8; ++w) s += red[w];
            lam = 1e-6f * s / 96.f;
        }
        __syncthreads();
        if (tid < 96) aug[tid*LDA + tid] += lam;
        __syncthreads();
    }

    // ---- blocked forward elimination, panel=16 (no pivoting; SPD) ----
    for (int kb = 0; kb < 96; kb += 16) {
        // panel factorization in registers on wave 0; pivot rows via shuffle broadcast
        if (tid < 64) {
            const int rA = lane, rB = lane + 64;
            const bool aAct = (rA >= kb);
            const bool bAct = (rB >= kb) && (rB < 96);
            float ra[16], rb[16], pv[16];
            #pragma unroll
            for (int m = 0; m < 16; ++m) {
                ra[m] = aAct ? aug[rA*LDA + kb + m] : 0.f;
                rb[m] = bAct ? aug[rB*LDA + kb + m] : 0.f;
            }
            #pragma unroll
            for (int kk = 0; kk < 16; ++kk) {
                const int pr = kb + kk;           // global pivot row (uniform)
                if (pr < 64) {
                    #pragma unroll
                    for (int m = 0; m < 16; ++m) pv[m] = __shfl(ra[m], pr);
                } else {
                    #pragma unroll
                    for (int m = 0; m < 16; ++m) pv[m] = __shfl(rb[m], pr - 64);
                }
                const float inv = __builtin_amdgcn_rcpf(pv[kk]);
                if (aAct && rA > pr) {
                    const float f = ra[kk] * inv; ra[kk] = f;
                    #pragma unroll
                    for (int m = 0; m < 16; ++m) if (m > kk) ra[m] = fmaf(-f, pv[m], ra[m]);
                }
                if (bAct && rB > pr) {
                    const float f = rb[kk] * inv; rb[kk] = f;
                    #pragma unroll
                    for (int m = 0; m < 16; ++m) if (m > kk) rb[m] = fmaf(-f, pv[m], rb[m]);
                }
            }
            #pragma unroll
            for (int m = 0; m < 16; ++m) {
                if (aAct) aug[rA*LDA + kb + m] = ra[m];
                if (bAct) aug[rB*LDA + kb + m] = rb[m];
            }
        }
        __syncthreads();

        // TRSM: L16x16 * u = raw for each trailing column (one col per thread)
        const int j = kb + 16 + tid;
        if (j < 106) {
            float u[16];
            #pragma unroll
            for (int m = 0; m < 16; ++m) u[m] = aug[(kb+m)*LDA + j];
            #pragma unroll
            for (int kk = 1; kk < 16; ++kk)
                #pragma unroll
                for (int m = 0; m < 16; ++m)
                    if (m < kk) u[kk] -= aug[(kb+kk)*LDA + (kb+m)] * u[m];
            #pragma unroll
            for (int m = 1; m < 16; ++m) aug[(kb+m)*LDA + j] = u[m];
        }
        __syncthreads();

        // rank-16 GEMM: 4 row-groups x 128 cols (8 waves); L reads wave-uniform broadcasts
        {
            const int g4 = tid >> 7, cl = tid & 127;
            const int jc = kb + 16 + cl;
            const bool act = (jc < 106);
            float u[16];
            #pragma unroll
            for (int m = 0; m < 16; ++m) u[m] = act ? aug[(kb+m)*LDA + jc] : 0.f;
            for (int i = kb + 16 + g4; i < 96; i += 4) {
                float L[16];
                #pragma unroll
                for (int m = 0; m < 16; ++m) L[m] = aug[i*LDA + kb + m];  // broadcast
                if (act) {
                    float s = aug[i*LDA + jc];
                    #pragma unroll
                    for (int m = 0; m < 16; ++m) s = fmaf(-L[m], u[m], s);
                    aug[i*LDA + jc] = s;
                }
            }
        }
        __syncthreads();
    }

    // ---- blocked back substitution (panel=16, 10 RHS) ----
    for (int pb = 80; pb >= 0; pb -= 16) {
        if (tid < 10) {   // in-register 16x16 upper-tri solve, one RHS column per thread
            const int c = 96 + tid;
            float x[16];
            #pragma unroll
            for (int mm = 0; mm < 16; ++mm) x[mm] = aug[(pb+mm)*LDA + c];
            #pragma unroll
            for (int kk = 15; kk >= 0; --kk) {
                float s = x[kk];
                #pragma unroll
                for (int mm = 0; mm < 16; ++mm)
                    if (mm > kk) s -= aug[(pb+kk)*LDA + (pb+mm)] * x[mm];
                x[kk] = s / aug[(pb+kk)*LDA + (pb+kk)];
            }
            #pragma unroll
            for (int mm = 0; mm < 16; ++mm) aug[(pb+mm)*LDA + c] = x[mm];
        }
        __syncthreads();
        if (tid < 500) {  // update rows above: rank-16
            const int c = 96 + (tid % 10);
            for (int i = tid / 10; i < pb; i += 50) {
                float s = aug[i*LDA + c];
                #pragma unroll
                for (int mm = 0; mm < 16; ++mm)
                    s -= aug[i*LDA + (pb+mm)] * aug[(pb+mm)*LDA + c];
                aug[i*LDA + c] = s;
            }
        }
        __syncthreads();
    }

    // ---- pred = K_ST^T @ alpha (alpha in aug cols 96..105) ----
    for (int idx = tid; idx < 960; idx += 512) {
        const int t = idx / 10, c = idx % 10;
        float s = 0.f;
        for (int n = 0; n < 96; ++n) s += Kst[n*96 + t] * aug[n*LDA + 96 + c];
        pred[idx] = s;
    }
}

extern "C" void kernel_launch(void* const* d_in, const int* in_sizes, int n_in,
                              void* d_out, int out_size, void* d_ws, size_t ws_size,
                              hipStream_t stream)
{
    (void)in_sizes; (void)n_in; (void)out_size; (void)ws_size;
    const float* U_S = (const float*)d_in[0];
    const float* V_S = (const float*)d_in[1];
    const float* X_S = (const float*)d_in[2];
    const float* y_S = (const float*)d_in[3];
    const float* A_T = (const float*)d_in[4];
    const float* X_T = (const float*)d_in[5];

    float* out  = (float*)d_out;
    float* pred = out;         // (96,10)
    float* Kss  = out + 960;   // (96,96)

    float* ws  = (float*)d_ws;
    float* wS  = ws;                       // 96*48
    float* d0S = ws + 4608;                // 96*48
    float* d0T = ws + 9216;                // 96*48
    float* zT  = ws + 13824;               // 96*48
    float* Kst = ws + 18432;               // 96*96
    unsigned short* XSh = (unsigned short*)(ws + 27648);    // 96*48*128 f16
    unsigned short* XTh = XSh + 96*6144;                    // 96*48*128 f16

    precompute_kernel<<<96, 256, 0, stream>>>(U_S, V_S, X_S, X_T, A_T,
                                              wS, d0S, d0T, zT, XSh, XTh);
    pair_kernel<<<3468, 256, 0, stream>>>(XSh, XTh, d0S, d0T, wS, zT, Kss, Kst);
    solve_pred_kernel<<<1, 512, 0, stream>>>(Kss, y_S, Kst, pred);
}